// Round 1
// baseline (7720.004 us; speedup 1.0000x reference)
//
#include <hip/hip_runtime.h>
#include <math.h>

#define H 200
#define PP 4
#define TT 4
#define BB 64
#define MM 1000
#define NEGV (-1e30f)

static const int ROWS = BB * MM;          // 64000
static const int UD   = 2 * H;            // 400
static const int G4H  = 4 * H;            // 800

// ---------------------------------------------------------------- init
__global__ __launch_bounds__(256) void k_init(const int* __restrict__ dmask,
    int* st_s, int* st_e, int* ms, int* me,
    float* h, float* c, float* out) {
  int b = blockIdx.x, t = threadIdx.x;
  __shared__ int red[256];
  int sum = 0;
  for (int m = t; m < MM; m += 256) sum += dmask[b * MM + m];
  red[t] = sum; __syncthreads();
  for (int s = 128; s > 0; s >>= 1) { if (t < s) red[t] += red[t + s]; __syncthreads(); }
  if (t == 0) { st_s[b] = 0; st_e[b] = red[0] - 1; ms[b] = 1; me[b] = 1; }
  for (int i = t; i < H; i += 256) { h[b * H + i] = 0.f; c[b * H + i] = 0.f; }
  if (b == 0 && t == 0) out[0] = 0.f;
}

// ---------------------------------------------------------------- LSTM
__global__ __launch_bounds__(1024) void k_lstm(
    const float* __restrict__ U, const int* __restrict__ st_s, const int* __restrict__ st_e,
    float* __restrict__ h, float* __restrict__ c,
    const float* __restrict__ w_ih, const float* __restrict__ w_hh,
    const float* __restrict__ b_ih, const float* __restrict__ b_hh,
    float* __restrict__ ucat, float* __restrict__ ue) {
  int b = blockIdx.x, t = threadIdx.x;
  __shared__ float x[800];
  __shared__ float hsh[H];
  __shared__ float g[800];
  int si = st_s[b], ei = st_e[b];
  const float* Us = U + ((size_t)b * MM + si) * UD;
  const float* Ue = U + ((size_t)b * MM + ei) * UD;
  for (int i = t; i < UD; i += 1024) { x[i] = Us[i]; x[UD + i] = Ue[i]; }
  for (int i = t; i < H; i += 1024) hsh[i] = h[b * H + i];
  __syncthreads();
  if (t < G4H) {
    float acc = b_ih[t] + b_hh[t];
    const float4* wi = (const float4*)(w_ih + (size_t)t * 800);
    for (int k = 0; k < 200; ++k) {
      float4 wv = wi[k]; const float* xv = &x[k * 4];
      acc = fmaf(wv.x, xv[0], acc); acc = fmaf(wv.y, xv[1], acc);
      acc = fmaf(wv.z, xv[2], acc); acc = fmaf(wv.w, xv[3], acc);
    }
    const float4* wh = (const float4*)(w_hh + (size_t)t * H);
    for (int k = 0; k < 50; ++k) {
      float4 wv = wh[k]; const float* hv = &hsh[k * 4];
      acc = fmaf(wv.x, hv[0], acc); acc = fmaf(wv.y, hv[1], acc);
      acc = fmaf(wv.z, hv[2], acc); acc = fmaf(wv.w, hv[3], acc);
    }
    g[t] = acc;
  }
  __syncthreads();
  if (t < H) {
    float ig = 1.f / (1.f + expf(-g[t]));
    float fg = 1.f / (1.f + expf(-g[H + t]));
    float gg = tanhf(g[2 * H + t]);
    float og = 1.f / (1.f + expf(-g[3 * H + t]));
    float cn = fg * c[b * H + t] + ig * gg;
    c[b * H + t] = cn;
    h[b * H + t] = og * tanhf(cn);
  }
  for (int i = t; i < 800; i += 1024) ucat[b * 800 + i] = x[i];
  for (int i = t; i < UD; i += 1024) ue[b * UD + i] = x[UD + i];
}

// ---------------------------------------------------------------- r + rcorr
// TAG 0: xc = [h, ucat]   TAG 1: xc = [h, U[b, st_s], ue]
template <int TAG>
__global__ __launch_bounds__(256) void k_r(
    const float* __restrict__ U, const int* __restrict__ st_s,
    const float* __restrict__ ucat, const float* __restrict__ ue,
    const float* __restrict__ h,
    const float* __restrict__ Wr, const float* __restrict__ W1,
    const float* __restrict__ b1, float* __restrict__ rcorr) {
  int b = blockIdx.x, t = threadIdx.x;
  __shared__ float xc[1000];
  __shared__ float r[H];
  for (int i = t; i < H; i += 256) xc[i] = h[b * H + i];
  if (TAG == 0) {
    for (int i = t; i < 800; i += 256) xc[H + i] = ucat[b * 800 + i];
  } else {
    const float* Us = U + ((size_t)b * MM + st_s[b]) * UD;
    for (int i = t; i < UD; i += 256) { xc[H + i] = Us[i]; xc[H + UD + i] = ue[b * UD + i]; }
  }
  __syncthreads();
  if (t < H) {
    float acc = 0.f;
    const float4* wr = (const float4*)(Wr + (size_t)t * 1000);
    for (int k = 0; k < 250; ++k) {
      float4 wv = wr[k]; const float* xv = &xc[k * 4];
      acc = fmaf(wv.x, xv[0], acc); acc = fmaf(wv.y, xv[1], acc);
      acc = fmaf(wv.z, xv[2], acc); acc = fmaf(wv.w, xv[3], acc);
    }
    r[t] = tanhf(acc);
  }
  __syncthreads();
  for (int j = t; j < 800; j += 256) {
    float acc = b1[j];
    const float4* w1 = (const float4*)(W1 + (size_t)j * 600 + 400);
    for (int k = 0; k < 50; ++k) {
      float4 wv = w1[k]; const float* rv = &r[k * 4];
      acc = fmaf(wv.x, rv[0], acc); acc = fmaf(wv.y, rv[1], acc);
      acc = fmaf(wv.z, rv[2], acc); acc = fmaf(wv.w, rv[3], acc);
    }
    rcorr[b * 800 + j] = acc;
  }
}

// ---------------------------------------------------------------- m1 (precomputed UW1 path)
__global__ __launch_bounds__(256) void k_m1(const float* __restrict__ uw1,
    const float* __restrict__ rcorr, float* __restrict__ m1) {
  int row = blockIdx.x, t = threadIdx.x;
  if (t >= H) return;
  int b = row / MM;
  float4 u = *(const float4*)(uw1 + (size_t)row * 800 + t * 4);
  float4 rc = *(const float4*)(rcorr + b * 800 + t * 4);
  float v = fmaxf(fmaxf(u.x + rc.x, u.y + rc.y), fmaxf(u.z + rc.z, u.w + rc.w));
  m1[(size_t)row * H + t] = v;
}

// ---------------------------------------------------------------- tiled fp32 GEMM (C = A @ B^T)
// MODE 0: plain write C (M x N).  MODE 1: + addend[b,800], maxP -> C (M x N/4).
// MODE 2: + bias[N], maxP -> C (M x N/4).
template <int MODE>
__global__ __launch_bounds__(256) void k_gemm(
    const float* __restrict__ A, int lda,
    const float* __restrict__ B, int ldb,
    const float* __restrict__ bias,
    const float* __restrict__ addend,
    float* __restrict__ C, int N, int K) {
  __shared__ float As[2][8][128];
  __shared__ float Bs[2][8][128];
  const int tid = threadIdx.x;
  const int tx = tid & 15, ty = tid >> 4;
  const int row0 = blockIdx.x * 128, n0 = blockIdx.y * 128;

  float acc[8][8];
#pragma unroll
  for (int i = 0; i < 8; ++i)
#pragma unroll
    for (int j = 0; j < 8; ++j) acc[i][j] = 0.f;

  const int lr = tid >> 1;        // 0..127
  const int lk = (tid & 1) * 4;   // 0 or 4
  const float* Ap = A + (size_t)(row0 + lr) * lda + lk;
  const int bcol = n0 + lr;
  const float* Bp = B + (size_t)bcol * ldb + lk;
  const bool bok = bcol < N;

  const int nk = K >> 3;
  float4 av = *(const float4*)Ap;
  float4 bv = bok ? *(const float4*)Bp : make_float4(0.f, 0.f, 0.f, 0.f);
  As[0][lk + 0][lr] = av.x; As[0][lk + 1][lr] = av.y;
  As[0][lk + 2][lr] = av.z; As[0][lk + 3][lr] = av.w;
  Bs[0][lk + 0][lr] = bv.x; Bs[0][lk + 1][lr] = bv.y;
  Bs[0][lk + 2][lr] = bv.z; Bs[0][lk + 3][lr] = bv.w;
  __syncthreads();

  for (int kt = 0; kt < nk; ++kt) {
    const int buf = kt & 1;
    if (kt + 1 < nk) {
      av = *(const float4*)(Ap + (kt + 1) * 8);
      bv = bok ? *(const float4*)(Bp + (kt + 1) * 8) : make_float4(0.f, 0.f, 0.f, 0.f);
    }
#pragma unroll
    for (int k = 0; k < 8; ++k) {
      float a[8], b[8];
      *(float4*)&a[0] = *(const float4*)&As[buf][k][ty * 4];
      *(float4*)&a[4] = *(const float4*)&As[buf][k][64 + ty * 4];
      *(float4*)&b[0] = *(const float4*)&Bs[buf][k][tx * 4];
      *(float4*)&b[4] = *(const float4*)&Bs[buf][k][64 + tx * 4];
#pragma unroll
      for (int i = 0; i < 8; ++i)
#pragma unroll
        for (int j = 0; j < 8; ++j) acc[i][j] = fmaf(a[i], b[j], acc[i][j]);
    }
    if (kt + 1 < nk) {
      const int nb = buf ^ 1;
      As[nb][lk + 0][lr] = av.x; As[nb][lk + 1][lr] = av.y;
      As[nb][lk + 2][lr] = av.z; As[nb][lk + 3][lr] = av.w;
      Bs[nb][lk + 0][lr] = bv.x; Bs[nb][lk + 1][lr] = bv.y;
      Bs[nb][lk + 2][lr] = bv.z; Bs[nb][lk + 3][lr] = bv.w;
    }
    __syncthreads();
  }

#pragma unroll
  for (int ih = 0; ih < 2; ++ih) {
#pragma unroll
    for (int i = 0; i < 4; ++i) {
      const int row = row0 + ih * 64 + ty * 4 + i;
      const int ai = ih * 4 + i;
      if (MODE == 0) {
#pragma unroll
        for (int jh = 0; jh < 2; ++jh) {
          const int col = n0 + jh * 64 + tx * 4;
          if (col < N) {
            float4 v = make_float4(acc[ai][jh * 4 + 0], acc[ai][jh * 4 + 1],
                                   acc[ai][jh * 4 + 2], acc[ai][jh * 4 + 3]);
            *(float4*)(C + (size_t)row * N + col) = v;
          }
        }
      } else {
        const int bidx = row / MM;
#pragma unroll
        for (int jh = 0; jh < 2; ++jh) {
          const int col = n0 + jh * 64 + tx * 4;
          if (col < N) {
            float m = -3.4e38f;
#pragma unroll
            for (int j = 0; j < 4; ++j) {
              float v = acc[ai][jh * 4 + j];
              if (MODE == 2) v += bias[col + j];
              if (MODE == 1) v += addend[bidx * 800 + col + j];
              m = fmaxf(m, v);
            }
            C[(size_t)row * (N >> 2) + (col >> 2)] = m;
          }
        }
      }
    }
  }
}

// ---------------------------------------------------------------- alpha
__global__ __launch_bounds__(256) void k_alpha(const float* __restrict__ m1,
    const float* __restrict__ m2, const float* __restrict__ W12,
    const float* __restrict__ b12, float* __restrict__ alpha) {
  int wid = threadIdx.x >> 6, lane = threadIdx.x & 63;
  size_t row = (size_t)blockIdx.x * 4 + wid;
  const float* r1 = m1 + row * H;
  const float* r2 = m2 + row * H;
  float a0 = 0.f, a1 = 0.f, a2 = 0.f, a3 = 0.f;
  for (int k = lane; k < H; k += 64) {
    float v1 = r1[k], v2 = r2[k];
    a0 += v1 * W12[0 * 400 + k] + v2 * W12[0 * 400 + 200 + k];
    a1 += v1 * W12[1 * 400 + k] + v2 * W12[1 * 400 + 200 + k];
    a2 += v1 * W12[2 * 400 + k] + v2 * W12[2 * 400 + 200 + k];
    a3 += v1 * W12[3 * 400 + k] + v2 * W12[3 * 400 + 200 + k];
  }
  for (int off = 32; off > 0; off >>= 1) {
    a0 += __shfl_down(a0, off); a1 += __shfl_down(a1, off);
    a2 += __shfl_down(a2, off); a3 += __shfl_down(a3, off);
  }
  if (lane == 0) {
    float m = fmaxf(fmaxf(a0 + b12[0], a1 + b12[1]), fmaxf(a2 + b12[2], a3 + b12[3]));
    alpha[row] = m;
  }
}

// ---------------------------------------------------------------- per-batch argmax + logsumexp
__global__ __launch_bounds__(256) void k_reduce(const float* __restrict__ alpha,
    const int* __restrict__ dmask, const int* __restrict__ span, int tag,
    int* __restrict__ idx_out, float* __restrict__ atgt_out) {
  int b = blockIdx.x, t = threadIdx.x;
  __shared__ float vals[MM];
  __shared__ float rv[256];
  __shared__ int ri[256];
  float bestv = -3.4e38f; int besti = 0x7fffffff;
  for (int m = t; m < MM; m += 256) {
    float v = alpha[b * MM + m];
    if (!dmask[b * MM + m]) v += NEGV;
    vals[m] = v;
    if (v > bestv || (v == bestv && m < besti)) { bestv = v; besti = m; }
  }
  rv[t] = bestv; ri[t] = besti; __syncthreads();
  for (int s = 128; s > 0; s >>= 1) {
    if (t < s) {
      float v2 = rv[t + s]; int i2 = ri[t + s];
      if (v2 > rv[t] || (v2 == rv[t] && i2 < ri[t])) { rv[t] = v2; ri[t] = i2; }
    }
    __syncthreads();
  }
  float vmax = rv[0]; int vidx = ri[0];
  __syncthreads();
  float se = 0.f;
  for (int m = t; m < MM; m += 256) se += expf(vals[m] - vmax);
  rv[t] = se; __syncthreads();
  for (int s = 128; s > 0; s >>= 1) { if (t < s) rv[t] += rv[t + s]; __syncthreads(); }
  if (t == 0) {
    int tgt = span[b * 2 + tag];
    atgt_out[b] = vals[tgt] - vmax - logf(rv[0]);
    idx_out[b] = vidx;
  }
}

// ---------------------------------------------------------------- state update + loss
__global__ __launch_bounds__(64) void k_update(const int* __restrict__ idx_buf,
    const float* __restrict__ atgt, int* __restrict__ st, int* __restrict__ mstate,
    float* __restrict__ pout, float* __restrict__ loss, int first) {
  int b = threadIdx.x;
  int idx = idx_buf[b];
  int sold = st[b], msold = mstate[b];
  int snew = first ? idx : (msold ? idx : 0);
  int msnew = first ? 1 : ((snew != (msold ? sold : 0)) ? 1 : 0);
  st[b] = snew; mstate[b] = msnew;
  if (msnew) pout[b] = (float)snew;
  float asum = atgt[b];
  float csum = (float)msnew;
  for (int off = 32; off > 0; off >>= 1) {
    asum += __shfl_down(asum, off);
    csum += __shfl_down(csum, off);
  }
  if (b == 0) loss[0] += (-asum / (float)BB) * csum / (float)(BB * TT);
}

// ---------------------------------------------------------------- launch
extern "C" void kernel_launch(void* const* d_in, const int* in_sizes, int n_in,
                              void* d_out, int out_size, void* d_ws, size_t ws_size,
                              hipStream_t stream) {
  const float* U     = (const float*)d_in[0];
  const int*   dmask = (const int*)d_in[1];
  const int*   span  = (const int*)d_in[2];
  const float* w_ih  = (const float*)d_in[3];
  const float* w_hh  = (const float*)d_in[4];
  const float* b_ih  = (const float*)d_in[5];
  const float* b_hh  = (const float*)d_in[6];
  const float* Wr[2]  = {(const float*)d_in[7],  (const float*)d_in[14]};
  const float* W1[2]  = {(const float*)d_in[8],  (const float*)d_in[15]};
  const float* b1[2]  = {(const float*)d_in[9],  (const float*)d_in[16]};
  const float* W2[2]  = {(const float*)d_in[10], (const float*)d_in[17]};
  const float* b2[2]  = {(const float*)d_in[11], (const float*)d_in[18]};
  const float* W12[2] = {(const float*)d_in[12], (const float*)d_in[19]};
  const float* b12[2] = {(const float*)d_in[13], (const float*)d_in[20]};
  float* out = (float*)d_out;

  char* w = (char*)d_ws;
  auto alloc = [&](size_t nbytes) {
    void* p = (void*)w;
    w += (nbytes + 255) & ~(size_t)255;
    return p;
  };
  float* m1    = (float*)alloc((size_t)ROWS * H * 4);
  float* m2    = (float*)alloc((size_t)ROWS * H * 4);
  float* alph  = (float*)alloc((size_t)BB * MM * 4);
  float* rcorr = (float*)alloc((size_t)BB * 800 * 4);
  float* ucat  = (float*)alloc((size_t)BB * 800 * 4);
  float* ue    = (float*)alloc((size_t)BB * UD * 4);
  float* hbuf  = (float*)alloc((size_t)BB * H * 4);
  float* cbuf  = (float*)alloc((size_t)BB * H * 4);
  float* atgt  = (float*)alloc((size_t)BB * 4);
  int* st_s = (int*)alloc(BB * 4);
  int* st_e = (int*)alloc(BB * 4);
  int* msb  = (int*)alloc(BB * 4);
  int* meb  = (int*)alloc(BB * 4);
  int* idxb = (int*)alloc(BB * 4);
  size_t base_used = (size_t)(w - (char*)d_ws);
  bool precomp = (ws_size > base_used) &&
                 ((ws_size - base_used) >= 2 * (size_t)ROWS * 800 * 4 + 1024);
  float* uw1[2] = {nullptr, nullptr};
  if (precomp) {
    uw1[0] = (float*)alloc((size_t)ROWS * 800 * 4);
    uw1[1] = (float*)alloc((size_t)ROWS * 800 * 4);
  }

  dim3 gg(ROWS / 128, (800 + 127) / 128);

  k_init<<<BB, 256, 0, stream>>>(dmask, st_s, st_e, msb, meb, hbuf, cbuf, out);
  if (precomp) {
    k_gemm<0><<<gg, 256, 0, stream>>>(U, UD, W1[0], 600, nullptr, nullptr, uw1[0], 800, 400);
    k_gemm<0><<<gg, 256, 0, stream>>>(U, UD, W1[1], 600, nullptr, nullptr, uw1[1], 800, 400);
  }

  for (int t = 0; t < TT; ++t) {
    int first = (t == 0) ? 1 : 0;
    k_lstm<<<BB, 1024, 0, stream>>>(U, st_s, st_e, hbuf, cbuf, w_ih, w_hh, b_ih, b_hh, ucat, ue);

    // ---- tag s ----
    k_r<0><<<BB, 256, 0, stream>>>(U, st_s, ucat, ue, hbuf, Wr[0], W1[0], b1[0], rcorr);
    if (precomp)
      k_m1<<<ROWS, 256, 0, stream>>>(uw1[0], rcorr, m1);
    else
      k_gemm<1><<<gg, 256, 0, stream>>>(U, UD, W1[0], 600, nullptr, rcorr, m1, 800, 400);
    k_gemm<2><<<gg, 256, 0, stream>>>(m1, H, W2[0], H, b2[0], nullptr, m2, 800, 200);
    k_alpha<<<ROWS / 4, 256, 0, stream>>>(m1, m2, W12[0], b12[0], alph);
    k_reduce<<<BB, 256, 0, stream>>>(alph, dmask, span, 0, idxb, atgt);
    k_update<<<1, 64, 0, stream>>>(idxb, atgt, st_s, msb, out + 1, out, first);

    // ---- tag e ----
    k_r<1><<<BB, 256, 0, stream>>>(U, st_s, ucat, ue, hbuf, Wr[1], W1[1], b1[1], rcorr);
    if (precomp)
      k_m1<<<ROWS, 256, 0, stream>>>(uw1[1], rcorr, m1);
    else
      k_gemm<1><<<gg, 256, 0, stream>>>(U, UD, W1[1], 600, nullptr, rcorr, m1, 800, 400);
    k_gemm<2><<<gg, 256, 0, stream>>>(m1, H, W2[1], H, b2[1], nullptr, m2, 800, 200);
    k_alpha<<<ROWS / 4, 256, 0, stream>>>(m1, m2, W12[1], b12[1], alph);
    k_reduce<<<BB, 256, 0, stream>>>(alph, dmask, span, 1, idxb, atgt);
    k_update<<<1, 64, 0, stream>>>(idxb, atgt, st_e, meb, out + 1 + BB, out, first);
  }
}